// Round 3
// baseline (716.278 us; speedup 1.0000x reference)
//
#include <hip/hip_runtime.h>
#include <hip/hip_bf16.h>

typedef unsigned short u16;
typedef __attribute__((ext_vector_type(8))) _Float16 half8;  // 8 fp16 in 4 VGPRs
typedef __attribute__((ext_vector_type(8))) unsigned short u16x8;
typedef __attribute__((ext_vector_type(4))) float f32x4;

static __device__ __forceinline__ u16 f2h(float v) {
  return __builtin_bit_cast(u16, (_Float16)v);
}
static __device__ __forceinline__ float h2f(u16 u) {
  return (float)__builtin_bit_cast(_Float16, u);
}

// async global->LDS, 16B per lane. LDS dest = wave-uniform base + lane*16.
static __device__ __forceinline__ void gll16(const void* g, void* l) {
  __builtin_amdgcn_global_load_lds(
      (const __attribute__((address_space(1))) unsigned int*)g,
      (__attribute__((address_space(3))) unsigned int*)l, 16, 0, 0);
}

template <int N>
static __device__ __forceinline__ void wait_vm() {
  if constexpr (N == 0) asm volatile("s_waitcnt vmcnt(0)" ::: "memory");
  else if constexpr (N == 4) asm volatile("s_waitcnt vmcnt(4)" ::: "memory");
  else if constexpr (N == 6) asm volatile("s_waitcnt vmcnt(6)" ::: "memory");
  else asm volatile("s_waitcnt vmcnt(8)" ::: "memory");
}

// ---------------------------------------------------------------------------
// gemm_bt: C[m][n] = sum_k A[m][k] * B[n][k]   (both operands K-contiguous,
// fp16). 128x128 tile, BK=32, 256 threads = 4 waves (2x2), wave tile 64x64.
// Triple-buffered LDS, prefetch-depth 2, COUNTED vmcnt (T4): at iter kt wait
// vmcnt(G) so stage(kt+1) stays in flight across the barrier; only the last
// iteration drains to 0. One s_barrier per K-step.
// XCD-chunked blockIdx swizzle ONLY when gridDim.z > 1 (per-batch chunking:
// per-XCD working set ~15 MB -> L2/L3 friendly). For z==1 grids (conv, pp)
// the natural x-fastest round-robin order has BETTER shared-L3 locality --
// r2 measured: chunked swizzle on conv = FETCH 152->184 MB, dur +15 us.
// ASPLIT: A given as hi+lo fp16; adds term Al*B.
// BSPLIT: B given as hi+lo fp16; adds term A*Bl.  (ll term dropped, ~2^-22)
// EPI: 0 = fp32 store; 1 = bias(m) + split2-fp16 store (Ch,Cl);
//      2 = fp32 + fp16 store; 3 = bias(n) + fp16 store; 4 = fp16 store
// ---------------------------------------------------------------------------
template <bool ASPLIT, bool BSPLIT, int EPI>
__global__ __launch_bounds__(256) void gemm_bt(
    const u16* __restrict__ A, const u16* __restrict__ Al,
    const u16* __restrict__ B, const u16* __restrict__ Bl,
    float* __restrict__ Cf, u16* __restrict__ Ch, u16* __restrict__ Cl,
    const float* __restrict__ bias0, const float* __restrict__ bias1,
    int biasSplit, int K, int lda, int ldb, int ldc,
    long long sA, long long sB, long long sC) {
  __shared__ __align__(16) u16 smA[3][(ASPLIT ? 2 : 1) * 128 * 32];
  __shared__ __align__(16) u16 smB[3][(BSPLIT ? 2 : 1) * 128 * 32];
  constexpr int G = 4 + (ASPLIT ? 2 : 0) + (BSPLIT ? 2 : 0);  // loads per stage

  const int tid = threadIdx.x;
  const int wave = tid >> 6, lane = tid & 63;
  const int wr = wave >> 1, wc = wave & 1;

  const int gx = gridDim.x, gy = gridDim.y;
  int bx, by;
  long long z;
  if (gridDim.z > 1) {
    // XCD-chunked swizzle: XCD k gets contiguous work range (z-major chunks)
    const int nwg = gx * gy * (int)gridDim.z;
    const int bid = (int)blockIdx.x + gx * ((int)blockIdx.y + gy * (int)blockIdx.z);
    const int w = (bid & 7) * (nwg >> 3) + (bid >> 3);
    bx = w % gx;
    const int rem = w / gx;
    by = rem % gy;
    z = rem / gy;
  } else {
    bx = blockIdx.x;
    by = blockIdx.y;
    z = 0;
  }

  A += z * sA;
  B += z * sB;
  if (ASPLIT) Al += z * sA;
  if (BSPLIT) Bl += z * sB;
  const long long tM = (long long)by * 128;
  const long long tN = (long long)bx * 128;
  const int r4 = lane >> 2, kc = lane & 3;

  const long long arow0 = (tM + wave * 16 + r4) * (long long)lda + kc * 8;
  const long long arow1 = arow0 + 64LL * lda;
  const long long brow0 = (tN + wave * 16 + r4) * (long long)ldb + kc * 8;
  const long long brow1 = brow0 + 64LL * ldb;

  // stage one 128x32 K-tile (hi + optional lo) into buffer bf
  auto stage = [&](int bf, long long ko) {
    u16* dA = &smA[bf][wave * 512];
    u16* dB = &smB[bf][wave * 512];
    gll16(A + arow0 + ko, dA);
    gll16(A + arow1 + ko, dA + 2048);
    gll16(B + brow0 + ko, dB);
    gll16(B + brow1 + ko, dB + 2048);
    if constexpr (ASPLIT) {
      gll16(Al + arow0 + ko, dA + 4096);
      gll16(Al + arow1 + ko, dA + 4096 + 2048);
    }
    if constexpr (BSPLIT) {
      gll16(Bl + brow0 + ko, dB + 4096);
      gll16(Bl + brow1 + ko, dB + 4096 + 2048);
    }
  };

  f32x4 acc[4][4];
#pragma unroll
  for (int i = 0; i < 4; i++)
#pragma unroll
    for (int j = 0; j < 4; j++) acc[i][j] = f32x4{0.f, 0.f, 0.f, 0.f};

  const int quad = lane >> 4, mr = lane & 15;
  const int nk = K >> 5;

  stage(0, 0);                  // prologue: tiles 0,1 into buffers 0,1
  if (nk > 1) stage(1, 32);

  int cur = 0;
  for (int kt = 0; kt < nk; ++kt) {
    // need stage(kt) landed. Newest in-flight is stage(kt+1) (G loads) while
    // kt < nk-1 -> allow G outstanding; final iter drains.
    if (kt < nk - 1) wait_vm<G>(); else wait_vm<0>();
    __builtin_amdgcn_s_barrier();
    asm volatile("" ::: "memory");  // keep LDS reads below the barrier

    half8 a[4], b[4];
#pragma unroll
    for (int i = 0; i < 4; i++)
      a[i] = *(const half8*)&smA[cur][(wr * 64 + i * 16 + mr) * 32 + quad * 8];
#pragma unroll
    for (int j = 0; j < 4; j++)
      b[j] = *(const half8*)&smB[cur][(wc * 64 + j * 16 + mr) * 32 + quad * 8];

    // prefetch tile kt+2 into the third buffer; it flies across the next
    // barrier (never waited to 0 until the last iteration).
    if (kt + 2 < nk) {
      int pf = cur + 2; if (pf >= 3) pf -= 3;
      stage(pf, (long long)(kt + 2) * 32);
    }

#pragma unroll
    for (int i = 0; i < 4; i++)
#pragma unroll
      for (int j = 0; j < 4; j++)
        acc[i][j] = __builtin_amdgcn_mfma_f32_16x16x32_f16(a[i], b[j], acc[i][j], 0, 0, 0);

    if constexpr (ASPLIT) {
      half8 al[4];
#pragma unroll
      for (int i = 0; i < 4; i++)
        al[i] = *(const half8*)&smA[cur][4096 + (wr * 64 + i * 16 + mr) * 32 + quad * 8];
#pragma unroll
      for (int i = 0; i < 4; i++)
#pragma unroll
        for (int j = 0; j < 4; j++)
          acc[i][j] = __builtin_amdgcn_mfma_f32_16x16x32_f16(al[i], b[j], acc[i][j], 0, 0, 0);
    }
    if constexpr (BSPLIT) {
      half8 bl[4];
#pragma unroll
      for (int j = 0; j < 4; j++)
        bl[j] = *(const half8*)&smB[cur][4096 + (wc * 64 + j * 16 + mr) * 32 + quad * 8];
#pragma unroll
      for (int i = 0; i < 4; i++)
#pragma unroll
        for (int j = 0; j < 4; j++)
          acc[i][j] = __builtin_amdgcn_mfma_f32_16x16x32_f16(a[i], bl[j], acc[i][j], 0, 0, 0);
    }
    cur = (cur == 2) ? 0 : cur + 1;
  }

  // epilogue: C/D map (verified): col = lane&15, row = quad*4 + reg
#pragma unroll
  for (int i = 0; i < 4; i++) {
#pragma unroll
    for (int j = 0; j < 4; j++) {
      const long long gn = tN + wc * 64 + j * 16 + mr;
#pragma unroll
      for (int p = 0; p < 4; p++) {
        const long long gm = tM + wr * 64 + i * 16 + quad * 4 + p;
        float v = acc[i][j][p];
        if constexpr (EPI == 1) v += (gm < biasSplit) ? bias0[gm] : bias1[gm - biasSplit];
        if constexpr (EPI == 3) v += (gn < biasSplit) ? bias0[gn] : bias1[gn - biasSplit];
        const long long off = z * sC + gm * ldc + gn;
        if constexpr (EPI == 0) {
          Cf[off] = v;
        } else if constexpr (EPI == 1) {
          u16 h = f2h(v);
          Ch[off] = h;
          Cl[off] = f2h(v - h2f(h));
        } else if constexpr (EPI == 2) {
          Cf[off] = v;
          Ch[off] = f2h(v);
        } else {
          Ch[off] = f2h(v);
        }
      }
    }
  }
  (void)biasSplit;
}

// ---------------------------------------------------------------------------
// im2col for stride-2 3x3 pad-1 conv -> fp16, vectorized 8 u16/thread.
// P[(b,oy,ox)][(c,ky,kx)], M=8*576=4608 rows, K=4608 cols
// ---------------------------------------------------------------------------
__global__ void im2col_kernel(const float* __restrict__ x, u16* __restrict__ Ph) {
  int idx = blockIdx.x * 256 + threadIdx.x;  // < 2654208 vec8's
  int m = idx / 576;                          // 576 vec8 per row
  int k0 = (idx - m * 576) * 8;
  int ox = m % 24, t2 = m / 24;
  int oy = t2 % 24, b = t2 / 24;
  int iy_base = 2 * oy - 1, ix_base = 2 * ox - 1;
  u16x8 out;
#pragma unroll
  for (int j = 0; j < 8; j++) {
    int k = k0 + j;
    int kx = k % 3, t = k / 3;
    int ky = t % 3, c = t / 3;
    int ix = ix_base + kx, iy = iy_base + ky;
    float v = 0.f;
    if (ix >= 0 && ix < 48 && iy >= 0 && iy < 48)
      v = x[((b * 512 + c) * 48 + iy) * 48 + ix];
    out[j] = f2h(v);
  }
  *(u16x8*)&Ph[(long long)idx * 8] = out;
}

// W split2-fp16, vectorized 8/thread: rows n<1024 -> Wqc, else Wkc.
__global__ void wprep_kernel(const float* __restrict__ Wqc, const float* __restrict__ Wkc,
                             u16* __restrict__ Wh, u16* __restrict__ Wl) {
  int idx = blockIdx.x * 256 + threadIdx.x;  // < 884736 vec8's
  long long base = (long long)idx * 8;
  int n = idx / 576;  // 576 vec8 per 4608-row
  const float* src = (n < 1024) ? &Wqc[base] : &Wkc[base - 1024LL * 4608];
  u16x8 h8, l8;
#pragma unroll
  for (int j = 0; j < 8; j++) {
    float v = src[j];
    u16 h = f2h(v);
    h8[j] = h;
    l8[j] = f2h(v - h2f(h));
  }
  *(u16x8*)&Wh[base] = h8;
  *(u16x8*)&Wl[base] = l8;
}

// Wqp||Wkp -> fp16 [dd][c], dd<64 qp else kp
__global__ void wp_prep(const float* __restrict__ Wqp, const float* __restrict__ Wkp,
                        u16* __restrict__ Wp) {
  int idx = blockIdx.x * 256 + threadIdx.x;  // < 128*512 = 65536
  int d = idx >> 9;
  float v = (d < 64) ? Wqp[idx] : Wkp[idx - 64 * 512];
  Wp[idx] = f2h(v);
}

// x (b,c,sp) -> xt[(b,sp)][c] fp16, tiled transpose
__global__ void xt_kernel(const float* __restrict__ x, u16* __restrict__ xt) {
  __shared__ float t[32][33];
  int b = blockIdx.z;
  int sp0 = blockIdx.x * 32, c0 = blockIdx.y * 32;
  int tx = threadIdx.x & 31, ty = threadIdx.x >> 5;  // 32 x 8
#pragma unroll
  for (int k = 0; k < 4; k++) {
    int c = c0 + ty + k * 8;
    t[ty + k * 8][tx] = x[((long long)(b * 512 + c)) * 2304 + sp0 + tx];
  }
  __syncthreads();
#pragma unroll
  for (int k = 0; k < 4; k++) {
    int sp = sp0 + ty + k * 8;
    xt[((long long)b * 2304 + sp) * 512 + c0 + tx] = f2h(t[tx][ty + k * 8]);
  }
}

// CAM softmax: attn = exp(rowmin - e)/sum  (== softmax(rowmax - e))
__global__ void softmax_cam(const float* __restrict__ E, u16* __restrict__ attn) {
  __shared__ float sm[4];
  const long long r = blockIdx.x;  // 8192 rows of 512
  const float* e = E + r * 512;
  int tid = threadIdx.x, wave = tid >> 6, lane = tid & 63;
  float v0 = e[tid], v1 = e[tid + 256];
  float mn = fminf(v0, v1);
#pragma unroll
  for (int o = 32; o; o >>= 1) mn = fminf(mn, __shfl_xor(mn, o));
  if (lane == 0) sm[wave] = mn;
  __syncthreads();
  mn = fminf(fminf(sm[0], sm[1]), fminf(sm[2], sm[3]));
  float p0 = __expf(mn - v0), p1 = __expf(mn - v1);
  float s = p0 + p1;
#pragma unroll
  for (int o = 32; o; o >>= 1) s += __shfl_xor(s, o);
  __syncthreads();
  if (lane == 0) sm[wave] = s;
  __syncthreads();
  float inv = 1.f / (sm[0] + sm[1] + sm[2] + sm[3]);
  attn[r * 512 + tid] = f2h(p0 * inv);
  attn[r * 512 + tid + 256] = f2h(p1 * inv);
}

// PAM softmax: in-place row softmax over 2304 cols (fp16), vectorized 16B/lane.
// 2304 = 256 threads * 8 + 32 threads * 8 tail.
__global__ void softmax_pam(u16* __restrict__ EP) {
  __shared__ float sm[4];
  const long long r = blockIdx.x;  // 18432 rows
  u16* e = EP + r * 2304;
  int tid = threadIdx.x, wave = tid >> 6, lane = tid & 63;
  u16x8 m8 = *(const u16x8*)&e[tid * 8];
  const bool hasTail = tid < 32;
  u16x8 t8;
  if (hasTail) t8 = *(const u16x8*)&e[2048 + tid * 8];
  float v[8], w[8];
  float mx = -1e30f;
#pragma unroll
  for (int k = 0; k < 8; k++) {
    v[k] = h2f(m8[k]);
    mx = fmaxf(mx, v[k]);
  }
  if (hasTail) {
#pragma unroll
    for (int k = 0; k < 8; k++) {
      w[k] = h2f(t8[k]);
      mx = fmaxf(mx, w[k]);
    }
  }
#pragma unroll
  for (int o = 32; o; o >>= 1) mx = fmaxf(mx, __shfl_xor(mx, o));
  if (lane == 0) sm[wave] = mx;
  __syncthreads();
  mx = fmaxf(fmaxf(sm[0], sm[1]), fmaxf(sm[2], sm[3]));
  float s = 0.f;
#pragma unroll
  for (int k = 0; k < 8; k++) {
    v[k] = __expf(v[k] - mx);
    s += v[k];
  }
  if (hasTail) {
#pragma unroll
    for (int k = 0; k < 8; k++) {
      w[k] = __expf(w[k] - mx);
      s += w[k];
    }
  }
#pragma unroll
  for (int o = 32; o; o >>= 1) s += __shfl_xor(s, o);
  __syncthreads();
  if (lane == 0) sm[wave] = s;
  __syncthreads();
  float inv = 1.f / (sm[0] + sm[1] + sm[2] + sm[3]);
#pragma unroll
  for (int k = 0; k < 8; k++) m8[k] = f2h(v[k] * inv);
  *(u16x8*)&e[tid * 8] = m8;
  if (hasTail) {
#pragma unroll
    for (int k = 0; k < 8; k++) t8[k] = f2h(w[k] * inv);
    *(u16x8*)&e[2048 + tid * 8] = t8;
  }
}

// ---------------------------------------------------------------------------
extern "C" void kernel_launch(void* const* d_in, const int* in_sizes, int n_in,
                              void* d_out, int out_size, void* d_ws, size_t ws_size,
                              hipStream_t stream) {
  const float* x   = (const float*)d_in[0];
  const float* Wqc = (const float*)d_in[1];
  const float* bqc = (const float*)d_in[2];
  const float* Wkc = (const float*)d_in[3];
  const float* bkc = (const float*)d_in[4];
  const float* Wqp = (const float*)d_in[5];
  const float* bqp = (const float*)d_in[6];
  const float* Wkp = (const float*)d_in[7];
  const float* bkp = (const float*)d_in[8];
  float* outc = (float*)d_out;                 // (8,1024,2304) fp32
  float* outp = outc + 8LL * 1024 * 2304;      // (8,1024,48,48) fp32

  if (ws_size < 195166208ULL) return;  // need ~186.1 MB scratch

  char* ws = (char*)d_ws;
  // lifetime-aliased arena (fp16 buffers as u16):
  u16*   P    = (u16*)(ws + 0);             // 4608x4608       [dead after conv]
  u16*   Wh   = (u16*)(ws + 42467328LL);    // 1536x4608 hi    [dead after conv]
  u16*   Wl   = (u16*)(ws + 56623104LL);    // 1536x4608 lo    [dead after conv]
  u16*   EP   = (u16*)(ws + 0);             // 8x2304x2304     [aliases P+W]
  u16*   qcth = (u16*)(ws + 84934656LL);    // 1536x4608 hi    [dead after energy]
  u16*   qctl = (u16*)(ws + 99090432LL);    // 1536x4608 lo    [dead after energy]
  u16*   pp   = (u16*)(ws + 84934656LL);    // 18432x128       [aliases qct]
  float* E    = (float*)(ws + 113246208LL); // 8x1024x512 fp32 [dead after softmax_cam]
  u16*   attn = (u16*)(ws + 130023424LL);   // 8x1024x512      [dead after out_c]
  u16*   xt   = (u16*)(ws + 138412032LL);   // 18432x512       [dead after pp gemm]
  u16*   ocb  = (u16*)(ws + 157286400LL);   // 8x1024x2304     [till end]
  u16*   Wp   = (u16*)(ws + 195035136LL);   // 128x512

  // prep
  wprep_kernel<<<3456, 256, 0, stream>>>(Wqc, Wkc, Wh, Wl);
  wp_prep<<<256, 256, 0, stream>>>(Wqp, Wkp, Wp);
  im2col_kernel<<<10368, 256, 0, stream>>>(x, P);
  xt_kernel<<<dim3(72, 16, 8), 256, 0, stream>>>(x, xt);

  // CAM convs (W-split 2-term): qct[ch][(b,sp)] = (Wh+Wl)*P^T + bias,
  // split2-fp16 out
  gemm_bt<true, false, 1><<<dim3(36, 12, 1), 256, 0, stream>>>(
      Wh, Wl, P, nullptr, nullptr, qcth, qctl, bqc, bkc, 1024,
      4608, 4608, 4608, 4608, 0, 0, 0);

  // energy[b][q][c] fp32 (3-term: hh + lh + hl)
  gemm_bt<true, true, 0><<<dim3(4, 8, 8), 256, 0, stream>>>(
      qcth, qctl, qcth + 1024LL * 4608, qctl + 1024LL * 4608,
      E, nullptr, nullptr,
      nullptr, nullptr, 0, 576, 4608, 4608, 512, 576, 576, 524288);

  softmax_cam<<<8192, 256, 0, stream>>>(E, attn);

  // out_c[b][q][sp] = attn @ x  (fp32 -> d_out, fp16 -> ocb)
  gemm_bt<false, false, 2><<<dim3(18, 8, 8), 256, 0, stream>>>(
      attn, nullptr, xt, nullptr, outc, ocb, nullptr,
      nullptr, nullptr, 0, 512, 512, 512, 2304, 524288, 1179648, 2359296);

  // qp/kp 1x1 convs: pp[(b,sp)][dd] = xt @ Wp^T + bias(dd)
  gemm_bt<false, false, 3><<<dim3(1, 144, 1), 256, 0, stream>>>(
      xt, nullptr, Wp, nullptr, nullptr, pp, nullptr,
      bqp, bkp, 64, 512, 512, 512, 128, 0, 0, 0);

  // energy_p[b][i][j] = qp(i) . kp(j), K=64, fp16 out
  gemm_bt<false, false, 4><<<dim3(18, 18, 8), 256, 0, stream>>>(
      pp, nullptr, pp + 64, nullptr, nullptr, EP, nullptr,
      nullptr, nullptr, 0, 64, 128, 128, 2304, 294912, 294912, 5308416);

  softmax_pam<<<18432, 256, 0, stream>>>(EP);

  // out_p[b][q][m] = out_c @ attn_p^T (fp32 -> d_out)
  gemm_bt<false, false, 0><<<dim3(18, 8, 8), 256, 0, stream>>>(
      ocb, nullptr, EP, nullptr, outp, nullptr, nullptr,
      nullptr, nullptr, 0, 2304, 2304, 2304, 2304, 2359296, 5308416, 2359296);

  (void)in_sizes; (void)n_in; (void)out_size;
}

// Round 4
// 657.677 us; speedup vs baseline: 1.0891x; 1.0891x over previous
//
#include <hip/hip_runtime.h>
#include <hip/hip_bf16.h>

typedef unsigned short u16;
typedef __attribute__((ext_vector_type(8))) _Float16 half8;  // 8 fp16 in 4 VGPRs
typedef __attribute__((ext_vector_type(4))) float f32x4;

static __device__ __forceinline__ u16 f2h(float v) {
  return __builtin_bit_cast(u16, (_Float16)v);
}
static __device__ __forceinline__ float h2f(u16 u) {
  return (float)__builtin_bit_cast(_Float16, u);
}

// async global->LDS, 16B per lane. LDS dest = wave-uniform base + lane*16.
static __device__ __forceinline__ void gll16(const void* g, void* l) {
  __builtin_amdgcn_global_load_lds(
      (const __attribute__((address_space(1))) unsigned int*)g,
      (__attribute__((address_space(3))) unsigned int*)l, 16, 0, 0);
}

template <int N>
static __device__ __forceinline__ void wait_vm() {
  if constexpr (N == 0) asm volatile("s_waitcnt vmcnt(0)" ::: "memory");
  else if constexpr (N == 4) asm volatile("s_waitcnt vmcnt(4)" ::: "memory");
  else if constexpr (N == 6) asm volatile("s_waitcnt vmcnt(6)" ::: "memory");
  else asm volatile("s_waitcnt vmcnt(8)" ::: "memory");
}

// ---------------------------------------------------------------------------
// gemm_bt: C[m][n] = sum_k A[m][k] * B[n][k]   (both operands K-contiguous,
// fp16). 128x128 tile, BK=32, 256 threads = 4 waves (2x2), wave tile 64x64.
// NBUF=2: classic double-buffer, vmcnt(0) + barrier each K-step. Best for
//   L2/L3-resident operands (conv, pp): latency short, smaller LDS keeps
//   3 blocks/CU headroom.  [r1: conv 154.5us vs r3 3-buf 159us]
// NBUF=3: prefetch-depth 2, COUNTED vmcnt (T4): at iter kt wait vmcnt(G) so
//   stage(kt+1) stays in flight across the barrier; drain only at the end.
//   Best for HBM-latency-bound z>1 GEMMs (out_p: left top-5 in r2/r3).
// XCD-chunked blockIdx swizzle ONLY when gridDim.z > 1 (per-batch chunking).
// For z==1 grids the natural order has better shared-L3 locality
// [r2: chunked swizzle on conv = FETCH 152->184 MB, dur +15us].
// ASPLIT: A given as hi+lo fp16; adds term Al*B.
// BSPLIT: B given as hi+lo fp16; adds term A*Bl.  (ll term dropped, ~2^-22)
// EPI: 0 = fp32 store; 1 = bias(m) + split2-fp16 store (Ch,Cl);
//      2 = fp32 + fp16 store; 3 = bias(n) + fp16 store; 4 = fp16 store
// ---------------------------------------------------------------------------
template <int NBUF, bool ASPLIT, bool BSPLIT, int EPI>
__global__ __launch_bounds__(256) void gemm_bt(
    const u16* __restrict__ A, const u16* __restrict__ Al,
    const u16* __restrict__ B, const u16* __restrict__ Bl,
    float* __restrict__ Cf, u16* __restrict__ Ch, u16* __restrict__ Cl,
    const float* __restrict__ bias0, const float* __restrict__ bias1,
    int biasSplit, int K, int lda, int ldb, int ldc,
    long long sA, long long sB, long long sC) {
  __shared__ __align__(16) u16 smA[NBUF][(ASPLIT ? 2 : 1) * 128 * 32];
  __shared__ __align__(16) u16 smB[NBUF][(BSPLIT ? 2 : 1) * 128 * 32];
  constexpr int G = 4 + (ASPLIT ? 2 : 0) + (BSPLIT ? 2 : 0);  // loads per stage
  constexpr int PD = NBUF - 1;                                 // prefetch depth

  const int tid = threadIdx.x;
  const int wave = tid >> 6, lane = tid & 63;
  const int wr = wave >> 1, wc = wave & 1;

  const int gx = gridDim.x, gy = gridDim.y;
  int bx, by;
  long long z;
  if (gridDim.z > 1) {
    // XCD-chunked swizzle: XCD k gets a contiguous work range
    const int nwg = gx * gy * (int)gridDim.z;
    const int bid = (int)blockIdx.x + gx * ((int)blockIdx.y + gy * (int)blockIdx.z);
    const int w = (bid & 7) * (nwg >> 3) + (bid >> 3);
    bx = w % gx;
    const int rem = w / gx;
    by = rem % gy;
    z = rem / gy;
  } else {
    bx = blockIdx.x;
    by = blockIdx.y;
    z = 0;
  }

  A += z * sA;
  B += z * sB;
  if (ASPLIT) Al += z * sA;
  if (BSPLIT) Bl += z * sB;
  const long long tM = (long long)by * 128;
  const long long tN = (long long)bx * 128;
  const int r4 = lane >> 2, kc = lane & 3;

  const long long arow0 = (tM + wave * 16 + r4) * (long long)lda + kc * 8;
  const long long arow1 = arow0 + 64LL * lda;
  const long long brow0 = (tN + wave * 16 + r4) * (long long)ldb + kc * 8;
  const long long brow1 = brow0 + 64LL * ldb;

  // stage one 128x32 K-tile (hi + optional lo) into buffer bf
  auto stage = [&](int bf, long long ko) {
    u16* dA = &smA[bf][wave * 512];
    u16* dB = &smB[bf][wave * 512];
    gll16(A + arow0 + ko, dA);
    gll16(A + arow1 + ko, dA + 2048);
    gll16(B + brow0 + ko, dB);
    gll16(B + brow1 + ko, dB + 2048);
    if constexpr (ASPLIT) {
      gll16(Al + arow0 + ko, dA + 4096);
      gll16(Al + arow1 + ko, dA + 4096 + 2048);
    }
    if constexpr (BSPLIT) {
      gll16(Bl + brow0 + ko, dB + 4096);
      gll16(Bl + brow1 + ko, dB + 4096 + 2048);
    }
  };

  f32x4 acc[4][4];
#pragma unroll
  for (int i = 0; i < 4; i++)
#pragma unroll
    for (int j = 0; j < 4; j++) acc[i][j] = f32x4{0.f, 0.f, 0.f, 0.f};

  const int quad = lane >> 4, mr = lane & 15;
  const int nk = K >> 5;

  stage(0, 0);  // prologue
  if constexpr (PD == 2) {
    if (nk > 1) stage(1, 32);
  }

  int cur = 0;
  for (int kt = 0; kt < nk; ++kt) {
    // NBUF==2: stage(kt) is the only in-flight group -> drain.
    // NBUF==3: stage(kt+1) may remain in flight (G loads) except last iter.
    if (PD == 2 && kt < nk - 1) wait_vm<G>(); else wait_vm<0>();
    __builtin_amdgcn_s_barrier();
    asm volatile("" ::: "memory");  // keep LDS reads below the barrier

    half8 a[4], b[4];
#pragma unroll
    for (int i = 0; i < 4; i++)
      a[i] = *(const half8*)&smA[cur][(wr * 64 + i * 16 + mr) * 32 + quad * 8];
#pragma unroll
    for (int j = 0; j < 4; j++)
      b[j] = *(const half8*)&smB[cur][(wc * 64 + j * 16 + mr) * 32 + quad * 8];

    // prefetch tile kt+PD; write-after-read safe: buf was last read PD
    // iterations ago and all waves have passed this barrier since.
    if (kt + PD < nk) {
      int pf = cur + PD; if (pf >= NBUF) pf -= NBUF;
      stage(pf, (long long)(kt + PD) * 32);
    }

#pragma unroll
    for (int i = 0; i < 4; i++)
#pragma unroll
      for (int j = 0; j < 4; j++)
        acc[i][j] = __builtin_amdgcn_mfma_f32_16x16x32_f16(a[i], b[j], acc[i][j], 0, 0, 0);

    if constexpr (ASPLIT) {
      half8 al[4];
#pragma unroll
      for (int i = 0; i < 4; i++)
        al[i] = *(const half8*)&smA[cur][4096 + (wr * 64 + i * 16 + mr) * 32 + quad * 8];
#pragma unroll
      for (int i = 0; i < 4; i++)
#pragma unroll
        for (int j = 0; j < 4; j++)
          acc[i][j] = __builtin_amdgcn_mfma_f32_16x16x32_f16(al[i], b[j], acc[i][j], 0, 0, 0);
    }
    if constexpr (BSPLIT) {
      half8 bl[4];
#pragma unroll
      for (int j = 0; j < 4; j++)
        bl[j] = *(const half8*)&smB[cur][4096 + (wc * 64 + j * 16 + mr) * 32 + quad * 8];
#pragma unroll
      for (int i = 0; i < 4; i++)
#pragma unroll
        for (int j = 0; j < 4; j++)
          acc[i][j] = __builtin_amdgcn_mfma_f32_16x16x32_f16(a[i], bl[j], acc[i][j], 0, 0, 0);
    }
    cur = (cur == NBUF - 1) ? 0 : cur + 1;
  }

  // epilogue: C/D map (verified): col = lane&15, row = quad*4 + reg
#pragma unroll
  for (int i = 0; i < 4; i++) {
#pragma unroll
    for (int j = 0; j < 4; j++) {
      const long long gn = tN + wc * 64 + j * 16 + mr;
#pragma unroll
      for (int p = 0; p < 4; p++) {
        const long long gm = tM + wr * 64 + i * 16 + quad * 4 + p;
        float v = acc[i][j][p];
        if constexpr (EPI == 1) v += (gm < biasSplit) ? bias0[gm] : bias1[gm - biasSplit];
        if constexpr (EPI == 3) v += (gn < biasSplit) ? bias0[gn] : bias1[gn - biasSplit];
        const long long off = z * sC + gm * ldc + gn;
        if constexpr (EPI == 0) {
          Cf[off] = v;
        } else if constexpr (EPI == 1) {
          u16 h = f2h(v);
          Ch[off] = h;
          Cl[off] = f2h(v - h2f(h));
        } else if constexpr (EPI == 2) {
          Cf[off] = v;
          Ch[off] = f2h(v);
        } else {
          Ch[off] = f2h(v);
        }
      }
    }
  }
  (void)biasSplit;
}

// ---------------------------------------------------------------------------
// im2col for stride-2 3x3 pad-1 conv -> fp16.
// P[(b,oy,ox)][(c,ky,kx)], M=8*576=4608 rows, K=4608 cols
// ---------------------------------------------------------------------------
__global__ void im2col_kernel(const float* __restrict__ x, u16* __restrict__ Ph) {
  int idx = blockIdx.x * 256 + threadIdx.x;  // < 4608*4608 = 21233664
  int k = idx % 4608;
  int m = idx / 4608;
  int kx = k % 3, t = k / 3;
  int ky = t % 3, c = t / 3;
  int ox = m % 24, t2 = m / 24;
  int oy = t2 % 24, b = t2 / 24;
  int ix = 2 * ox - 1 + kx, iy = 2 * oy - 1 + ky;
  float v = 0.f;
  if (ix >= 0 && ix < 48 && iy >= 0 && iy < 48)
    v = x[((b * 512 + c) * 48 + iy) * 48 + ix];
  Ph[idx] = f2h(v);
}

// W split2-fp16: rows n<1024 -> Wqc, else Wkc. [n][k=c*9+ky*3+kx] native layout.
__global__ void wprep_kernel(const float* __restrict__ Wqc, const float* __restrict__ Wkc,
                             u16* __restrict__ Wh, u16* __restrict__ Wl) {
  int idx = blockIdx.x * 256 + threadIdx.x;  // < 1536*4608 = 7077888
  int n = idx / 4608;
  float v = (n < 1024) ? Wqc[idx] : Wkc[idx - 1024 * 4608];
  u16 h = f2h(v);
  Wh[idx] = h;
  Wl[idx] = f2h(v - h2f(h));
}

// Wqp||Wkp -> fp16 [dd][c], dd<64 qp else kp
__global__ void wp_prep(const float* __restrict__ Wqp, const float* __restrict__ Wkp,
                        u16* __restrict__ Wp) {
  int idx = blockIdx.x * 256 + threadIdx.x;  // < 128*512 = 65536
  int d = idx >> 9;
  float v = (d < 64) ? Wqp[idx] : Wkp[idx - 64 * 512];
  Wp[idx] = f2h(v);
}

// x (b,c,sp) -> xt[(b,sp)][c] fp16, tiled transpose
__global__ void xt_kernel(const float* __restrict__ x, u16* __restrict__ xt) {
  __shared__ float t[32][33];
  int b = blockIdx.z;
  int sp0 = blockIdx.x * 32, c0 = blockIdx.y * 32;
  int tx = threadIdx.x & 31, ty = threadIdx.x >> 5;  // 32 x 8
#pragma unroll
  for (int k = 0; k < 4; k++) {
    int c = c0 + ty + k * 8;
    t[ty + k * 8][tx] = x[((long long)(b * 512 + c)) * 2304 + sp0 + tx];
  }
  __syncthreads();
#pragma unroll
  for (int k = 0; k < 4; k++) {
    int sp = sp0 + ty + k * 8;
    xt[((long long)b * 2304 + sp) * 512 + c0 + tx] = f2h(t[tx][ty + k * 8]);
  }
}

// CAM softmax: attn = exp(rowmin - e)/sum  (== softmax(rowmax - e))
__global__ void softmax_cam(const float* __restrict__ E, u16* __restrict__ attn) {
  __shared__ float sm[4];
  const long long r = blockIdx.x;  // 8192 rows of 512
  const float* e = E + r * 512;
  int tid = threadIdx.x, wave = tid >> 6, lane = tid & 63;
  float v0 = e[tid], v1 = e[tid + 256];
  float mn = fminf(v0, v1);
#pragma unroll
  for (int o = 32; o; o >>= 1) mn = fminf(mn, __shfl_xor(mn, o));
  if (lane == 0) sm[wave] = mn;
  __syncthreads();
  mn = fminf(fminf(sm[0], sm[1]), fminf(sm[2], sm[3]));
  float p0 = __expf(mn - v0), p1 = __expf(mn - v1);
  float s = p0 + p1;
#pragma unroll
  for (int o = 32; o; o >>= 1) s += __shfl_xor(s, o);
  __syncthreads();
  if (lane == 0) sm[wave] = s;
  __syncthreads();
  float inv = 1.f / (sm[0] + sm[1] + sm[2] + sm[3]);
  attn[r * 512 + tid] = f2h(p0 * inv);
  attn[r * 512 + tid + 256] = f2h(p1 * inv);
}

// PAM softmax: in-place row softmax over 2304 cols (fp16)
__global__ void softmax_pam(u16* __restrict__ EP) {
  __shared__ float sm[4];
  const long long r = blockIdx.x;  // 18432 rows
  u16* e = EP + r * 2304;
  int tid = threadIdx.x, wave = tid >> 6, lane = tid & 63;
  float v[9];
#pragma unroll
  for (int k = 0; k < 9; k++) v[k] = h2f(e[tid + 256 * k]);
  float mx = v[0];
#pragma unroll
  for (int k = 1; k < 9; k++) mx = fmaxf(mx, v[k]);
#pragma unroll
  for (int o = 32; o; o >>= 1) mx = fmaxf(mx, __shfl_xor(mx, o));
  if (lane == 0) sm[wave] = mx;
  __syncthreads();
  mx = fmaxf(fmaxf(sm[0], sm[1]), fmaxf(sm[2], sm[3]));
  float s = 0.f;
#pragma unroll
  for (int k = 0; k < 9; k++) {
    v[k] = __expf(v[k] - mx);
    s += v[k];
  }
#pragma unroll
  for (int o = 32; o; o >>= 1) s += __shfl_xor(s, o);
  __syncthreads();
  if (lane == 0) sm[wave] = s;
  __syncthreads();
  float inv = 1.f / (sm[0] + sm[1] + sm[2] + sm[3]);
#pragma unroll
  for (int k = 0; k < 9; k++) e[tid + 256 * k] = f2h(v[k] * inv);
}

// ---------------------------------------------------------------------------
extern "C" void kernel_launch(void* const* d_in, const int* in_sizes, int n_in,
                              void* d_out, int out_size, void* d_ws, size_t ws_size,
                              hipStream_t stream) {
  const float* x   = (const float*)d_in[0];
  const float* Wqc = (const float*)d_in[1];
  const float* bqc = (const float*)d_in[2];
  const float* Wkc = (const float*)d_in[3];
  const float* bkc = (const float*)d_in[4];
  const float* Wqp = (const float*)d_in[5];
  const float* bqp = (const float*)d_in[6];
  const float* Wkp = (const float*)d_in[7];
  const float* bkp = (const float*)d_in[8];
  float* outc = (float*)d_out;                 // (8,1024,2304) fp32
  float* outp = outc + 8LL * 1024 * 2304;      // (8,1024,48,48) fp32

  if (ws_size < 195166208ULL) return;  // need ~186.1 MB scratch

  char* ws = (char*)d_ws;
  // lifetime-aliased arena (fp16 buffers as u16):
  u16*   P    = (u16*)(ws + 0);             // 4608x4608       [dead after conv]
  u16*   Wh   = (u16*)(ws + 42467328LL);    // 1536x4608 hi    [dead after conv]
  u16*   Wl   = (u16*)(ws + 56623104LL);    // 1536x4608 lo    [dead after conv]
  u16*   EP   = (u16*)(ws + 0);             // 8x2304x2304     [aliases P+W]
  u16*   qcth = (u16*)(ws + 84934656LL);    // 1536x4608 hi    [dead after energy]
  u16*   qctl = (u16*)(ws + 99090432LL);    // 1536x4608 lo    [dead after energy]
  u16*   pp   = (u16*)(ws + 84934656LL);    // 18432x128       [aliases qct]
  float* E    = (float*)(ws + 113246208LL); // 8x1024x512 fp32 [dead after softmax_cam]
  u16*   attn = (u16*)(ws + 130023424LL);   // 8x1024x512      [dead after out_c]
  u16*   xt   = (u16*)(ws + 138412032LL);   // 18432x512       [dead after pp gemm]
  u16*   ocb  = (u16*)(ws + 157286400LL);   // 8x1024x2304     [till end]
  u16*   Wp   = (u16*)(ws + 195035136LL);   // 128x512

  // prep
  wprep_kernel<<<27648, 256, 0, stream>>>(Wqc, Wkc, Wh, Wl);
  wp_prep<<<256, 256, 0, stream>>>(Wqp, Wkp, Wp);
  im2col_kernel<<<82944, 256, 0, stream>>>(x, P);
  xt_kernel<<<dim3(72, 16, 8), 256, 0, stream>>>(x, xt);

  // CAM convs (W-split 2-term): qct[ch][(b,sp)] = (Wh+Wl)*P^T + bias,
  // split2-fp16 out.  L3-resident -> NBUF=2 (48KB LDS, 3 blocks/CU headroom)
  gemm_bt<2, true, false, 1><<<dim3(36, 12, 1), 256, 0, stream>>>(
      Wh, Wl, P, nullptr, nullptr, qcth, qctl, bqc, bkc, 1024,
      4608, 4608, 4608, 4608, 0, 0, 0);

  // energy[b][q][c] fp32 (3-term: hh + lh + hl)
  gemm_bt<3, true, true, 0><<<dim3(4, 8, 8), 256, 0, stream>>>(
      qcth, qctl, qcth + 1024LL * 4608, qctl + 1024LL * 4608,
      E, nullptr, nullptr,
      nullptr, nullptr, 0, 576, 4608, 4608, 512, 576, 576, 524288);

  softmax_cam<<<8192, 256, 0, stream>>>(E, attn);

  // out_c[b][q][sp] = attn @ x  (fp32 -> d_out, fp16 -> ocb)
  gemm_bt<3, false, false, 2><<<dim3(18, 8, 8), 256, 0, stream>>>(
      attn, nullptr, xt, nullptr, outc, ocb, nullptr,
      nullptr, nullptr, 0, 512, 512, 512, 2304, 524288, 1179648, 2359296);

  // qp/kp 1x1 convs: pp[(b,sp)][dd] = xt @ Wp^T + bias(dd)
  gemm_bt<2, false, false, 3><<<dim3(1, 144, 1), 256, 0, stream>>>(
      xt, nullptr, Wp, nullptr, nullptr, pp, nullptr,
      bqp, bkp, 64, 512, 512, 512, 128, 0, 0, 0);

  // energy_p[b][i][j] = qp(i) . kp(j), K=64, fp16 out
  gemm_bt<3, false, false, 4><<<dim3(18, 18, 8), 256, 0, stream>>>(
      pp, nullptr, pp + 64, nullptr, nullptr, EP, nullptr,
      nullptr, nullptr, 0, 64, 128, 128, 2304, 294912, 294912, 5308416);

  softmax_pam<<<18432, 256, 0, stream>>>(EP);

  // out_p[b][q][m] = out_c @ attn_p^T (fp32 -> d_out)
  gemm_bt<3, false, false, 0><<<dim3(18, 8, 8), 256, 0, stream>>>(
      ocb, nullptr, EP, nullptr, outp, nullptr, nullptr,
      nullptr, nullptr, 0, 2304, 2304, 2304, 2304, 2359296, 5308416, 2359296);

  (void)in_sizes; (void)n_in; (void)out_size;
}

// Round 5
// 608.271 us; speedup vs baseline: 1.1776x; 1.0812x over previous
//
#include <hip/hip_runtime.h>
#include <hip/hip_bf16.h>

typedef unsigned short u16;
typedef __attribute__((ext_vector_type(8))) _Float16 half8;  // 8 fp16 in 4 VGPRs
typedef __attribute__((ext_vector_type(8))) unsigned short u16x8;
typedef __attribute__((ext_vector_type(4))) float f32x4;

static __device__ __forceinline__ u16 f2h(float v) {
  return __builtin_bit_cast(u16, (_Float16)v);
}
static __device__ __forceinline__ float h2f(u16 u) {
  return (float)__builtin_bit_cast(_Float16, u);
}

// async global->LDS, 16B per lane. LDS dest = wave-uniform base + lane*16.
static __device__ __forceinline__ void gll16(const void* g, void* l) {
  __builtin_amdgcn_global_load_lds(
      (const __attribute__((address_space(1))) unsigned int*)g,
      (__attribute__((address_space(3))) unsigned int*)l, 16, 0, 0);
}

template <int N>
static __device__ __forceinline__ void wait_vm() {
  if constexpr (N == 0) asm volatile("s_waitcnt vmcnt(0)" ::: "memory");
  else if constexpr (N == 4) asm volatile("s_waitcnt vmcnt(4)" ::: "memory");
  else if constexpr (N == 6) asm volatile("s_waitcnt vmcnt(6)" ::: "memory");
  else asm volatile("s_waitcnt vmcnt(8)" ::: "memory");
}

// ---------------------------------------------------------------------------
// gemm_bt: C[m][n] = sum_k A[m][k] * B[n][k]   (both operands K-contiguous,
// fp16). 128x128 tile, BK=32, 256 threads = 4 waves (2x2), wave tile 64x64.
// NBUF=2: classic double-buffer, vmcnt(0) + barrier each K-step. Best for
//   L2/L3-resident operands (conv, pp): latency short, smaller LDS keeps
//   3 blocks/CU headroom.  [r1: conv 154.5us vs r3 3-buf 159us]
// NBUF=3: prefetch-depth 2, COUNTED vmcnt (T4): at iter kt wait vmcnt(G) so
//   stage(kt+1) stays in flight across the barrier; drain only at the end.
//   Best for HBM-latency-bound z>1 GEMMs (out_p: left top-5 in r2/r3).
// XCD-chunked blockIdx swizzle ONLY when gridDim.z > 1 (per-batch chunking).
// For z==1 grids the natural order has better shared-L3 locality
// [r2: chunked swizzle on conv = FETCH 152->184 MB, dur +15us].
// ASPLIT: A given as hi+lo fp16; adds term Al*B.
// BSPLIT: B given as hi+lo fp16; adds term A*Bl.  (ll term dropped, ~2^-22)
// EPI: 0 = fp32 store; 1 = bias(m) + split2-fp16 store (Ch,Cl);
//      2 = fp32 + fp16 store; 3 = bias(n) + fp16 store; 4 = fp16 store
// ---------------------------------------------------------------------------
template <int NBUF, bool ASPLIT, bool BSPLIT, int EPI>
__global__ __launch_bounds__(256) void gemm_bt(
    const u16* __restrict__ A, const u16* __restrict__ Al,
    const u16* __restrict__ B, const u16* __restrict__ Bl,
    float* __restrict__ Cf, u16* __restrict__ Ch, u16* __restrict__ Cl,
    const float* __restrict__ bias0, const float* __restrict__ bias1,
    int biasSplit, int K, int lda, int ldb, int ldc,
    long long sA, long long sB, long long sC) {
  __shared__ __align__(16) u16 smA[NBUF][(ASPLIT ? 2 : 1) * 128 * 32];
  __shared__ __align__(16) u16 smB[NBUF][(BSPLIT ? 2 : 1) * 128 * 32];
  constexpr int G = 4 + (ASPLIT ? 2 : 0) + (BSPLIT ? 2 : 0);  // loads per stage
  constexpr int PD = NBUF - 1;                                 // prefetch depth

  const int tid = threadIdx.x;
  const int wave = tid >> 6, lane = tid & 63;
  const int wr = wave >> 1, wc = wave & 1;

  const int gx = gridDim.x, gy = gridDim.y;
  int bx, by;
  long long z;
  if (gridDim.z > 1) {
    // XCD-chunked swizzle: XCD k gets a contiguous work range
    const int nwg = gx * gy * (int)gridDim.z;
    const int bid = (int)blockIdx.x + gx * ((int)blockIdx.y + gy * (int)blockIdx.z);
    const int w = (bid & 7) * (nwg >> 3) + (bid >> 3);
    bx = w % gx;
    const int rem = w / gx;
    by = rem % gy;
    z = rem / gy;
  } else {
    bx = blockIdx.x;
    by = blockIdx.y;
    z = 0;
  }

  A += z * sA;
  B += z * sB;
  if (ASPLIT) Al += z * sA;
  if (BSPLIT) Bl += z * sB;
  const long long tM = (long long)by * 128;
  const long long tN = (long long)bx * 128;
  const int r4 = lane >> 2, kc = lane & 3;

  const long long arow0 = (tM + wave * 16 + r4) * (long long)lda + kc * 8;
  const long long arow1 = arow0 + 64LL * lda;
  const long long brow0 = (tN + wave * 16 + r4) * (long long)ldb + kc * 8;
  const long long brow1 = brow0 + 64LL * ldb;

  // stage one 128x32 K-tile (hi + optional lo) into buffer bf
  auto stage = [&](int bf, long long ko) {
    u16* dA = &smA[bf][wave * 512];
    u16* dB = &smB[bf][wave * 512];
    gll16(A + arow0 + ko, dA);
    gll16(A + arow1 + ko, dA + 2048);
    gll16(B + brow0 + ko, dB);
    gll16(B + brow1 + ko, dB + 2048);
    if constexpr (ASPLIT) {
      gll16(Al + arow0 + ko, dA + 4096);
      gll16(Al + arow1 + ko, dA + 4096 + 2048);
    }
    if constexpr (BSPLIT) {
      gll16(Bl + brow0 + ko, dB + 4096);
      gll16(Bl + brow1 + ko, dB + 4096 + 2048);
    }
  };

  f32x4 acc[4][4];
#pragma unroll
  for (int i = 0; i < 4; i++)
#pragma unroll
    for (int j = 0; j < 4; j++) acc[i][j] = f32x4{0.f, 0.f, 0.f, 0.f};

  const int quad = lane >> 4, mr = lane & 15;
  const int nk = K >> 5;

  stage(0, 0);  // prologue
  if constexpr (PD == 2) {
    if (nk > 1) stage(1, 32);
  }

  int cur = 0;
  for (int kt = 0; kt < nk; ++kt) {
    // NBUF==2: stage(kt) is the only in-flight group -> drain.
    // NBUF==3: stage(kt+1) may remain in flight (G loads) except last iter.
    if (PD == 2 && kt < nk - 1) wait_vm<G>(); else wait_vm<0>();
    __builtin_amdgcn_s_barrier();
    asm volatile("" ::: "memory");  // keep LDS reads below the barrier

    half8 a[4], b[4];
#pragma unroll
    for (int i = 0; i < 4; i++)
      a[i] = *(const half8*)&smA[cur][(wr * 64 + i * 16 + mr) * 32 + quad * 8];
#pragma unroll
    for (int j = 0; j < 4; j++)
      b[j] = *(const half8*)&smB[cur][(wc * 64 + j * 16 + mr) * 32 + quad * 8];

    // prefetch tile kt+PD; write-after-read safe: buf was last read PD
    // iterations ago and all waves have passed this barrier since.
    if (kt + PD < nk) {
      int pf = cur + PD; if (pf >= NBUF) pf -= NBUF;
      stage(pf, (long long)(kt + PD) * 32);
    }

#pragma unroll
    for (int i = 0; i < 4; i++)
#pragma unroll
      for (int j = 0; j < 4; j++)
        acc[i][j] = __builtin_amdgcn_mfma_f32_16x16x32_f16(a[i], b[j], acc[i][j], 0, 0, 0);

    if constexpr (ASPLIT) {
      half8 al[4];
#pragma unroll
      for (int i = 0; i < 4; i++)
        al[i] = *(const half8*)&smA[cur][4096 + (wr * 64 + i * 16 + mr) * 32 + quad * 8];
#pragma unroll
      for (int i = 0; i < 4; i++)
#pragma unroll
        for (int j = 0; j < 4; j++)
          acc[i][j] = __builtin_amdgcn_mfma_f32_16x16x32_f16(al[i], b[j], acc[i][j], 0, 0, 0);
    }
    if constexpr (BSPLIT) {
      half8 bl[4];
#pragma unroll
      for (int j = 0; j < 4; j++)
        bl[j] = *(const half8*)&smB[cur][4096 + (wc * 64 + j * 16 + mr) * 32 + quad * 8];
#pragma unroll
      for (int i = 0; i < 4; i++)
#pragma unroll
        for (int j = 0; j < 4; j++)
          acc[i][j] = __builtin_amdgcn_mfma_f32_16x16x32_f16(a[i], bl[j], acc[i][j], 0, 0, 0);
    }
    cur = (cur == NBUF - 1) ? 0 : cur + 1;
  }

  // epilogue: C/D map (verified): col = lane&15, row = quad*4 + reg
#pragma unroll
  for (int i = 0; i < 4; i++) {
#pragma unroll
    for (int j = 0; j < 4; j++) {
      const long long gn = tN + wc * 64 + j * 16 + mr;
#pragma unroll
      for (int p = 0; p < 4; p++) {
        const long long gm = tM + wr * 64 + i * 16 + quad * 4 + p;
        float v = acc[i][j][p];
        if constexpr (EPI == 1) v += (gm < biasSplit) ? bias0[gm] : bias1[gm - biasSplit];
        if constexpr (EPI == 3) v += (gn < biasSplit) ? bias0[gn] : bias1[gn - biasSplit];
        const long long off = z * sC + gm * ldc + gn;
        if constexpr (EPI == 0) {
          Cf[off] = v;
        } else if constexpr (EPI == 1) {
          u16 h = f2h(v);
          Ch[off] = h;
          Cl[off] = f2h(v - h2f(h));
        } else if constexpr (EPI == 2) {
          Cf[off] = v;
          Ch[off] = f2h(v);
        } else {
          Ch[off] = f2h(v);
        }
      }
    }
  }
  (void)biasSplit;
}

// ---------------------------------------------------------------------------
// im2col in PERMUTED k layout k' = g*512 + c  (g = ky*3+kx), reading rows of
// xt (fp16, c-contiguous) -> pure coalesced row copy, 16B/lane both sides.
// Each wave handles one (m, g) pair x 512 channels: 1KB contiguous r+w.
// P values are bit-identical to the old path (xt already = f2h(x)).
// ---------------------------------------------------------------------------
__global__ void im2col_kernel(const u16* __restrict__ xt, u16* __restrict__ Ph) {
  int idx = blockIdx.x * 256 + threadIdx.x;  // < 4608*576 = 2654208
  int m = idx / 576;
  int r = idx - m * 576;
  int g = r >> 6;
  int c0 = (r & 63) * 8;
  int b = m / 576, t = m - b * 576;
  int oy = t / 24, ox = t - oy * 24;
  int ky = g / 3, kx = g - ky * 3;
  int iy = 2 * oy - 1 + ky, ix = 2 * ox - 1 + kx;
  u16x8 v = u16x8{0, 0, 0, 0, 0, 0, 0, 0};
  if (iy >= 0 && iy < 48 && ix >= 0 && ix < 48)
    v = *(const u16x8*)&xt[((long long)b * 2304 + iy * 48 + ix) * 512 + c0];
  *(u16x8*)&Ph[(long long)m * 4608 + (long long)g * 512 + c0] = v;
}

// W split2-fp16 in the SAME permuted k' = g*512 + c layout. Reads are
// stride-9 fp32 gathers (W is small, 28MB); writes 16B/lane vectorized.
__global__ void wprep_kernel(const float* __restrict__ Wqc, const float* __restrict__ Wkc,
                             u16* __restrict__ Wh, u16* __restrict__ Wl) {
  int idx = blockIdx.x * 256 + threadIdx.x;  // < 1536*576 = 884736
  int n = idx / 576;
  int r = idx - n * 576;
  int g = r >> 6;
  int c0 = (r & 63) * 8;
  const float* src = (n < 1024)
      ? &Wqc[((long long)n * 512 + c0) * 9 + g]
      : &Wkc[(((long long)n - 1024) * 512 + c0) * 9 + g];
  u16x8 h8, l8;
#pragma unroll
  for (int j = 0; j < 8; j++) {
    float v = src[j * 9];
    u16 h = f2h(v);
    h8[j] = h;
    l8[j] = f2h(v - h2f(h));
  }
  long long out = (long long)n * 4608 + (long long)g * 512 + c0;
  *(u16x8*)&Wh[out] = h8;
  *(u16x8*)&Wl[out] = l8;
}

// Wqp||Wkp -> fp16 [dd][c], dd<64 qp else kp
__global__ void wp_prep(const float* __restrict__ Wqp, const float* __restrict__ Wkp,
                        u16* __restrict__ Wp) {
  int idx = blockIdx.x * 256 + threadIdx.x;  // < 128*512 = 65536
  int d = idx >> 9;
  float v = (d < 64) ? Wqp[idx] : Wkp[idx - 64 * 512];
  Wp[idx] = f2h(v);
}

// x (b,c,sp) -> xt[(b,sp)][c] fp16, tiled transpose
__global__ void xt_kernel(const float* __restrict__ x, u16* __restrict__ xt) {
  __shared__ float t[32][33];
  int b = blockIdx.z;
  int sp0 = blockIdx.x * 32, c0 = blockIdx.y * 32;
  int tx = threadIdx.x & 31, ty = threadIdx.x >> 5;  // 32 x 8
#pragma unroll
  for (int k = 0; k < 4; k++) {
    int c = c0 + ty + k * 8;
    t[ty + k * 8][tx] = x[((long long)(b * 512 + c)) * 2304 + sp0 + tx];
  }
  __syncthreads();
#pragma unroll
  for (int k = 0; k < 4; k++) {
    int sp = sp0 + ty + k * 8;
    xt[((long long)b * 2304 + sp) * 512 + c0 + tx] = f2h(t[tx][ty + k * 8]);
  }
}

// CAM softmax: attn = exp(rowmin - e)/sum  (== softmax(rowmax - e))
__global__ void softmax_cam(const float* __restrict__ E, u16* __restrict__ attn) {
  __shared__ float sm[4];
  const long long r = blockIdx.x;  // 8192 rows of 512
  const float* e = E + r * 512;
  int tid = threadIdx.x, wave = tid >> 6, lane = tid & 63;
  float v0 = e[tid], v1 = e[tid + 256];
  float mn = fminf(v0, v1);
#pragma unroll
  for (int o = 32; o; o >>= 1) mn = fminf(mn, __shfl_xor(mn, o));
  if (lane == 0) sm[wave] = mn;
  __syncthreads();
  mn = fminf(fminf(sm[0], sm[1]), fminf(sm[2], sm[3]));
  float p0 = __expf(mn - v0), p1 = __expf(mn - v1);
  float s = p0 + p1;
#pragma unroll
  for (int o = 32; o; o >>= 1) s += __shfl_xor(s, o);
  __syncthreads();
  if (lane == 0) sm[wave] = s;
  __syncthreads();
  float inv = 1.f / (sm[0] + sm[1] + sm[2] + sm[3]);
  attn[r * 512 + tid] = f2h(p0 * inv);
  attn[r * 512 + tid + 256] = f2h(p1 * inv);
}

// PAM softmax: in-place row softmax over 2304 cols (fp16), 16B/lane.
// 2304 = 256 threads * 8 + 32 threads * 8 tail (threads 0-31 of wave 0).
__global__ void softmax_pam(u16* __restrict__ EP) {
  __shared__ float sm[4];
  const long long r = blockIdx.x;  // 18432 rows
  u16* e = EP + r * 2304;
  int tid = threadIdx.x, wave = tid >> 6, lane = tid & 63;
  u16x8 m8 = *(const u16x8*)&e[tid * 8];
  const bool hasTail = tid < 32;
  u16x8 t8;
  if (hasTail) t8 = *(const u16x8*)&e[2048 + tid * 8];
  float v[8], w[8];
  float mx = -1e30f;
#pragma unroll
  for (int k = 0; k < 8; k++) {
    v[k] = h2f(m8[k]);
    mx = fmaxf(mx, v[k]);
  }
  if (hasTail) {
#pragma unroll
    for (int k = 0; k < 8; k++) {
      w[k] = h2f(t8[k]);
      mx = fmaxf(mx, w[k]);
    }
  }
#pragma unroll
  for (int o = 32; o; o >>= 1) mx = fmaxf(mx, __shfl_xor(mx, o));
  if (lane == 0) sm[wave] = mx;
  __syncthreads();
  mx = fmaxf(fmaxf(sm[0], sm[1]), fmaxf(sm[2], sm[3]));
  float s = 0.f;
#pragma unroll
  for (int k = 0; k < 8; k++) {
    v[k] = __expf(v[k] - mx);
    s += v[k];
  }
  if (hasTail) {
#pragma unroll
    for (int k = 0; k < 8; k++) {
      w[k] = __expf(w[k] - mx);
      s += w[k];
    }
  }
#pragma unroll
  for (int o = 32; o; o >>= 1) s += __shfl_xor(s, o);
  __syncthreads();
  if (lane == 0) sm[wave] = s;
  __syncthreads();
  float inv = 1.f / (sm[0] + sm[1] + sm[2] + sm[3]);
#pragma unroll
  for (int k = 0; k < 8; k++) m8[k] = f2h(v[k] * inv);
  *(u16x8*)&e[tid * 8] = m8;
  if (hasTail) {
#pragma unroll
    for (int k = 0; k < 8; k++) t8[k] = f2h(w[k] * inv);
    *(u16x8*)&e[2048 + tid * 8] = t8;
  }
}

// ---------------------------------------------------------------------------
extern "C" void kernel_launch(void* const* d_in, const int* in_sizes, int n_in,
                              void* d_out, int out_size, void* d_ws, size_t ws_size,
                              hipStream_t stream) {
  const float* x   = (const float*)d_in[0];
  const float* Wqc = (const float*)d_in[1];
  const float* bqc = (const float*)d_in[2];
  const float* Wkc = (const float*)d_in[3];
  const float* bkc = (const float*)d_in[4];
  const float* Wqp = (const float*)d_in[5];
  const float* bqp = (const float*)d_in[6];
  const float* Wkp = (const float*)d_in[7];
  const float* bkp = (const float*)d_in[8];
  float* outc = (float*)d_out;                 // (8,1024,2304) fp32
  float* outp = outc + 8LL * 1024 * 2304;      // (8,1024,48,48) fp32

  if (ws_size < 195166208ULL) return;  // need ~186.1 MB scratch

  char* ws = (char*)d_ws;
  // lifetime-aliased arena (fp16 buffers as u16):
  u16*   P    = (u16*)(ws + 0);             // 4608x4608       [dead after conv]
  u16*   Wh   = (u16*)(ws + 42467328LL);    // 1536x4608 hi    [dead after conv]
  u16*   Wl   = (u16*)(ws + 56623104LL);    // 1536x4608 lo    [dead after conv]
  u16*   EP   = (u16*)(ws + 0);             // 8x2304x2304     [aliases P+W]
  u16*   qcth = (u16*)(ws + 84934656LL);    // 1536x4608 hi    [dead after energy]
  u16*   qctl = (u16*)(ws + 99090432LL);    // 1536x4608 lo    [dead after energy]
  u16*   pp   = (u16*)(ws + 84934656LL);    // 18432x128       [aliases qct]
  float* E    = (float*)(ws + 113246208LL); // 8x1024x512 fp32 [dead after softmax_cam]
  u16*   attn = (u16*)(ws + 130023424LL);   // 8x1024x512      [dead after out_c]
  u16*   xt   = (u16*)(ws + 138412032LL);   // 18432x512       [dead after pp gemm]
  u16*   ocb  = (u16*)(ws + 157286400LL);   // 8x1024x2304     [till end]
  u16*   Wp   = (u16*)(ws + 195035136LL);   // 128x512

  // prep (xt must precede im2col: im2col copies from xt)
  xt_kernel<<<dim3(72, 16, 8), 256, 0, stream>>>(x, xt);
  wp_prep<<<256, 256, 0, stream>>>(Wqp, Wkp, Wp);
  wprep_kernel<<<3456, 256, 0, stream>>>(Wqc, Wkc, Wh, Wl);
  im2col_kernel<<<10368, 256, 0, stream>>>(xt, P);

  // CAM convs (W-split 2-term): qct[ch][(b,sp)] = (Wh+Wl)*P^T + bias,
  // split2-fp16 out.  L3-resident -> NBUF=2 (48KB LDS, 3 blocks/CU headroom)
  gemm_bt<2, true, false, 1><<<dim3(36, 12, 1), 256, 0, stream>>>(
      Wh, Wl, P, nullptr, nullptr, qcth, qctl, bqc, bkc, 1024,
      4608, 4608, 4608, 4608, 0, 0, 0);

  // energy[b][q][c] fp32 (3-term: hh + lh + hl)
  gemm_bt<3, true, true, 0><<<dim3(4, 8, 8), 256, 0, stream>>>(
      qcth, qctl, qcth + 1024LL * 4608, qctl + 1024LL * 4608,
      E, nullptr, nullptr,
      nullptr, nullptr, 0, 576, 4608, 4608, 512, 576, 576, 524288);

  softmax_cam<<<8192, 256, 0, stream>>>(E, attn);

  // out_c[b][q][sp] = attn @ x  (fp32 -> d_out, fp16 -> ocb)
  gemm_bt<3, false, false, 2><<<dim3(18, 8, 8), 256, 0, stream>>>(
      attn, nullptr, xt, nullptr, outc, ocb, nullptr,
      nullptr, nullptr, 0, 512, 512, 512, 2304, 524288, 1179648, 2359296);

  // qp/kp 1x1 convs: pp[(b,sp)][dd] = xt @ Wp^T + bias(dd)
  gemm_bt<2, false, false, 3><<<dim3(1, 144, 1), 256, 0, stream>>>(
      xt, nullptr, Wp, nullptr, nullptr, pp, nullptr,
      bqp, bkp, 64, 512, 512, 512, 128, 0, 0, 0);

  // energy_p[b][i][j] = qp(i) . kp(j), K=64, fp16 out
  gemm_bt<3, false, false, 4><<<dim3(18, 18, 8), 256, 0, stream>>>(
      pp, nullptr, pp + 64, nullptr, nullptr, EP, nullptr,
      nullptr, nullptr, 0, 64, 128, 128, 2304, 294912, 294912, 5308416);

  softmax_pam<<<18432, 256, 0, stream>>>(EP);

  // out_p[b][q][m] = out_c @ attn_p^T (fp32 -> d_out)
  gemm_bt<3, false, false, 0><<<dim3(18, 8, 8), 256, 0, stream>>>(
      ocb, nullptr, EP, nullptr, outp, nullptr, nullptr,
      nullptr, nullptr, 0, 2304, 2304, 2304, 2304, 2359296, 5308416, 2359296);

  (void)in_sizes; (void)n_in; (void)out_size;
}